// Round 1
// baseline (848.601 us; speedup 1.0000x reference)
//
#include <hip/hip_runtime.h>

// fastmax attention: b=4,h=16,n=1024,d=64, fp32.
// scores = (1 + qn.kn + qn.rpe[i-j+n-1]) * causal ; out = scores@(v+0.1*noise) / rowsum
// Block: 256 threads, one 64x64 query tile; loop over causal 64-col K/V tiles.

constexpr int N  = 1024;
constexpr int D  = 64;
constexpr int BM = 64;
constexpr int BN = 64;
constexpr int LDQ = 64;   // stride (floats) of transposed 64x64 tiles (no pad: LDS budget = 64KB exact)
constexpr int LDR = 128;  // stride of rpe window tile (127 cols used, 128 for aligned float4)

__global__ __launch_bounds__(256, 2)
void fastmax_kernel(const float* __restrict__ qg,
                    const float* __restrict__ kg,
                    const float* __restrict__ vg,
                    const float* __restrict__ ng,
                    const float* __restrict__ rg,
                    float* __restrict__ og) {
    __shared__ float Qs[D * LDQ];    // Qs[t][r]  (transposed: t = d-dim, r = query row)
    __shared__ float KSs[D * LDQ];   // Ks[t][c] transposed; reused as Ss_T[c][r]
    __shared__ float RVs[D * LDR];   // rpe window transposed Rs[t][w]; reused as Vs[c][dc] (stride LDQ)

    const int tid = threadIdx.x;
    const int bh  = blockIdx.y;
    const int bix = blockIdx.x;
    const int i0  = bix * BM;
    const int tx  = tid & 15;
    const int ty  = tid >> 4;
    const int Rr  = ty * 4;        // this thread's 4 S/O rows
    const int Cc  = tx * 4;        // this thread's 4 S cols / 4 O d-cols

    const size_t base = (size_t)bh * N * D;

    // ---- load Q tile (transposed scatter) ----
    const float4* q4 = (const float4*)(qg + base + (size_t)i0 * D);
    for (int u = tid; u < BM * (D / 4); u += 256) {
        int row = u >> 4;
        int c4  = (u & 15) * 4;
        float4 val = q4[u];
        Qs[(c4 + 0) * LDQ + row] = val.x;
        Qs[(c4 + 1) * LDQ + row] = val.y;
        Qs[(c4 + 2) * LDQ + row] = val.z;
        Qs[(c4 + 3) * LDQ + row] = val.w;
    }
    __syncthreads();
    // ---- normalize Q rows: 4 threads per row (quarters of d), shfl-combine ----
    {
        int r = tid >> 2, qt = tid & 3;
        int t0 = qt * 16;
        float ss = 0.f;
        #pragma unroll
        for (int t = 0; t < 16; ++t) {
            float x = Qs[(t0 + t) * LDQ + r];
            ss += x * x;
        }
        ss += __shfl_xor(ss, 1, 4);
        ss += __shfl_xor(ss, 2, 4);
        float rn = rsqrtf(ss);
        #pragma unroll
        for (int t = 0; t < 16; ++t)
            Qs[(t0 + t) * LDQ + r] *= rn;
    }
    __syncthreads();

    float o_acc[4][4] = {};
    float pden[4] = {};

    for (int jt = 0; jt <= bix; ++jt) {
        const int j0 = jt * BN;
        // ---- load K tile (transposed scatter) ----
        const float4* k4 = (const float4*)(kg + base + (size_t)j0 * D);
        for (int u = tid; u < BN * (D / 4); u += 256) {
            int row = u >> 4;
            int c4  = (u & 15) * 4;
            float4 val = k4[u];
            KSs[(c4 + 0) * LDQ + row] = val.x;
            KSs[(c4 + 1) * LDQ + row] = val.y;
            KSs[(c4 + 2) * LDQ + row] = val.z;
            KSs[(c4 + 3) * LDQ + row] = val.w;
        }
        // ---- load rpe window transposed: w in [0,126], global row rel0+w ----
        // rel(i,j) = i - j + N-1 = rel0 + (r - c + 63), rel0 = i0 - j0 + N-1-63
        const int rel0 = i0 - j0 + (N - 1) - 63;
        const float4* r4 = (const float4*)rg;
        for (int u = tid; u < 127 * (D / 4); u += 256) {
            int w  = u >> 4;
            int c4 = (u & 15) * 4;
            float4 val = r4[(size_t)(rel0 + w) * (D / 4) + (u & 15)];
            RVs[(c4 + 0) * LDR + w] = val.x;
            RVs[(c4 + 1) * LDR + w] = val.y;
            RVs[(c4 + 2) * LDR + w] = val.z;
            RVs[(c4 + 3) * LDR + w] = val.w;
        }
        __syncthreads();
        // ---- normalize K rows ----
        {
            int r = tid >> 2, qt = tid & 3;
            int t0 = qt * 16;
            float ss = 0.f;
            #pragma unroll
            for (int t = 0; t < 16; ++t) {
                float x = KSs[(t0 + t) * LDQ + r];
                ss += x * x;
            }
            ss += __shfl_xor(ss, 1, 4);
            ss += __shfl_xor(ss, 2, 4);
            float rn = rsqrtf(ss);
            #pragma unroll
            for (int t = 0; t < 16; ++t)
                KSs[(t0 + t) * LDQ + r] *= rn;
        }
        __syncthreads();

        // ---- S[r][c] = 1 + sum_t q[t][r]*(k[t][c] + rpe[t][r-c+63]), then mask ----
        float s[4][4] = {};
        const int wb = Rr - Cc + 60;   // w for (rr,cc): wb + rr - cc + 3, in [0,126]
        for (int t = 0; t < D; ++t) {
            float4 qv  = *(const float4*)&Qs[t * LDQ + Rr];
            float4 kv  = *(const float4*)&KSs[t * LDQ + Cc];
            float4 rv0 = *(const float4*)&RVs[t * LDR + wb];
            float4 rv1 = *(const float4*)&RVs[t * LDR + wb + 4];
            float qa[4] = {qv.x, qv.y, qv.z, qv.w};
            float ka[4] = {kv.x, kv.y, kv.z, kv.w};
            float ra[8] = {rv0.x, rv0.y, rv0.z, rv0.w, rv1.x, rv1.y, rv1.z, rv1.w};
            #pragma unroll
            for (int rr = 0; rr < 4; ++rr)
                #pragma unroll
                for (int cc = 0; cc < 4; ++cc)
                    s[rr][cc] += qa[rr] * (ka[cc] + ra[rr - cc + 3]);
        }
        const bool diag = (jt == bix);
        #pragma unroll
        for (int rr = 0; rr < 4; ++rr)
            #pragma unroll
            for (int cc = 0; cc < 4; ++cc) {
                float val = s[rr][cc] + 1.0f;
                if (diag && (Cc + cc) > (Rr + rr)) val = 0.f;
                s[rr][cc] = val;
                pden[rr] += val;
            }
        __syncthreads();   // everyone done reading Ks/Rs

        // ---- stash S transposed into KSs; load V(+noise) into RVs ----
        #pragma unroll
        for (int rr = 0; rr < 4; ++rr)
            #pragma unroll
            for (int cc = 0; cc < 4; ++cc)
                KSs[(Cc + cc) * LDQ + (Rr + rr)] = s[rr][cc];
        const float4* v4 = (const float4*)(vg + base + (size_t)j0 * D);
        const float4* n4 = (const float4*)(ng + base + (size_t)j0 * D);
        for (int u = tid; u < BN * (D / 4); u += 256) {
            int row = u >> 4;
            int c4  = (u & 15) * 4;
            float4 vv = v4[u];
            float4 nn = n4[u];
            float4 res;
            res.x = vv.x + 0.1f * nn.x;
            res.y = vv.y + 0.1f * nn.y;
            res.z = vv.z + 0.1f * nn.z;
            res.w = vv.w + 0.1f * nn.w;
            *(float4*)&RVs[row * LDQ + c4] = res;
        }
        __syncthreads();

        // ---- O[r][dc] += sum_c Ss_T[c][r] * Vs[c][dc] ----
        for (int c = 0; c < BN; ++c) {
            float4 sv = *(const float4*)&KSs[c * LDQ + Rr];
            float4 vv = *(const float4*)&RVs[c * LDQ + Cc];
            float sa[4] = {sv.x, sv.y, sv.z, sv.w};
            float va[4] = {vv.x, vv.y, vv.z, vv.w};
            #pragma unroll
            for (int rr = 0; rr < 4; ++rr)
                #pragma unroll
                for (int cc = 0; cc < 4; ++cc)
                    o_acc[rr][cc] += sa[rr] * va[cc];
        }
        __syncthreads();   // before next tile overwrites KSs/RVs
    }

    // ---- reduce row denominators across the 16 threads sharing ty; write out ----
    float* outp = og + base + (size_t)i0 * D;
    #pragma unroll
    for (int rr = 0; rr < 4; ++rr) {
        float dsum = pden[rr];
        dsum += __shfl_xor(dsum, 1, 16);
        dsum += __shfl_xor(dsum, 2, 16);
        dsum += __shfl_xor(dsum, 4, 16);
        dsum += __shfl_xor(dsum, 8, 16);
        float inv = 1.0f / dsum;
        float4 res;
        res.x = o_acc[rr][0] * inv;
        res.y = o_acc[rr][1] * inv;
        res.z = o_acc[rr][2] * inv;
        res.w = o_acc[rr][3] * inv;
        *(float4*)&outp[(size_t)(Rr + rr) * D + Cc] = res;
    }
}

extern "C" void kernel_launch(void* const* d_in, const int* in_sizes, int n_in,
                              void* d_out, int out_size, void* d_ws, size_t ws_size,
                              hipStream_t stream) {
    const float* q   = (const float*)d_in[0];
    const float* k   = (const float*)d_in[1];
    const float* v   = (const float*)d_in[2];
    const float* dn  = (const float*)d_in[3];
    const float* rpe = (const float*)d_in[4];
    float* out = (float*)d_out;
    const int bh = in_sizes[0] / (N * D);   // 4*16 = 64
    dim3 grid(N / BM, bh);
    fastmax_kernel<<<grid, dim3(256), 0, stream>>>(q, k, v, dn, rpe, out);
}

// Round 3
// 298.029 us; speedup vs baseline: 2.8474x; 2.8474x over previous
//
#include <hip/hip_runtime.h>

// fastmax attention via split-precision MFMA (bf16x3: hi*hi + hi*lo + lo*hi),
// fp32 accum. b=4,h=16,n=1024,d=64.
// S = (1 + qn.kn + qn.rpe[i-j+n-1]) * causal ; out = S@(v+0.1*noise) / rowsum(S)
// Per block: one 64x64 Q tile; loop over causal 64-col K/V tiles.
// rpe bias: B127[r][w] = qn_r . rpe[rel0+w] (64x128x64 GEMM), LDS round-trip
// in fp32, gather bias[r][c] = B127[r][r-c+63].

constexpr int N   = 1024;
constexpr int D   = 64;
constexpr int BM  = 64;
constexpr int LDT = 72;   // ushort stride for bf16 tiles
constexpr int LDB = 68;   // float stride for Bst

typedef short short8  __attribute__((ext_vector_type(8)));
typedef float float4v __attribute__((ext_vector_type(4)));

__device__ __forceinline__ ushort f2bf(float x) {
    union { float f; unsigned u; } un; un.f = x;
    unsigned r = un.u + 0x7fffu + ((un.u >> 16) & 1u);   // RNE
    return (ushort)(r >> 16);
}
__device__ __forceinline__ float bf2f(ushort h) {
    union { unsigned u; float f; } un; un.u = ((unsigned)h) << 16;
    return un.f;
}
__device__ __forceinline__ void split2(float x, ushort& h, ushort& l) {
    h = f2bf(x);
    l = f2bf(x - bf2f(h));
}

// stage one 64x64 fp32 tile -> l2-normalized rows -> bf16 hi/lo tiles
__device__ __forceinline__ void stage_norm_split(const float* __restrict__ src,
                                                 ushort* dh, ushort* dl, int tid) {
    const int row = tid >> 2, seg = tid & 3;
    const float4* p = (const float4*)(src + (size_t)row * D + seg * 16);
    float4 f[4] = {p[0], p[1], p[2], p[3]};
    float ss = 0.f;
#pragma unroll
    for (int i = 0; i < 4; ++i)
        ss += f[i].x * f[i].x + f[i].y * f[i].y + f[i].z * f[i].z + f[i].w * f[i].w;
    ss += __shfl_xor(ss, 1, 4);
    ss += __shfl_xor(ss, 2, 4);
    const float rn = rsqrtf(ss);
    unsigned* ph = (unsigned*)&dh[row * LDT + seg * 16];
    unsigned* pl = (unsigned*)&dl[row * LDT + seg * 16];
#pragma unroll
    for (int i = 0; i < 4; ++i) {
        float va[4] = {f[i].x * rn, f[i].y * rn, f[i].z * rn, f[i].w * rn};
        ushort hh[4], ll[4];
#pragma unroll
        for (int j = 0; j < 4; ++j) split2(va[j], hh[j], ll[j]);
        ph[2 * i]     = (unsigned)hh[0] | ((unsigned)hh[1] << 16);
        ph[2 * i + 1] = (unsigned)hh[2] | ((unsigned)hh[3] << 16);
        pl[2 * i]     = (unsigned)ll[0] | ((unsigned)ll[1] << 16);
        pl[2 * i + 1] = (unsigned)ll[2] | ((unsigned)ll[3] << 16);
    }
}

// 6-MFMA split product: C += A_hi*B_hi + A_hi*B_lo + A_lo*B_hi  (two K=32 halves)
__device__ __forceinline__ float4v mm6(short8 ah0, short8 ah1, short8 al0, short8 al1,
                                       const ushort* Bh, const ushort* Bl, int off,
                                       float4v c) {
    short8 bh0 = *(const short8*)&Bh[off];
    short8 bh1 = *(const short8*)&Bh[off + 32];
    short8 bl0 = *(const short8*)&Bl[off];
    short8 bl1 = *(const short8*)&Bl[off + 32];
    c = __builtin_amdgcn_mfma_f32_16x16x32_bf16(ah0, bh0, c, 0, 0, 0);
    c = __builtin_amdgcn_mfma_f32_16x16x32_bf16(ah1, bh1, c, 0, 0, 0);
    c = __builtin_amdgcn_mfma_f32_16x16x32_bf16(ah0, bl0, c, 0, 0, 0);
    c = __builtin_amdgcn_mfma_f32_16x16x32_bf16(ah1, bl1, c, 0, 0, 0);
    c = __builtin_amdgcn_mfma_f32_16x16x32_bf16(al0, bh0, c, 0, 0, 0);
    c = __builtin_amdgcn_mfma_f32_16x16x32_bf16(al1, bh1, c, 0, 0, 0);
    return c;
}

__global__ __launch_bounds__(256, 2)
void fastmax_mfma3(const float* __restrict__ qg, const float* __restrict__ kg,
                   const float* __restrict__ vg, const float* __restrict__ ng,
                   const float* __restrict__ rg, float* __restrict__ og) {
    // region A (36864 B): rpe hi/lo tiles during QR; Bst fp32 after; Q staging at start
    __shared__ __align__(16) char regA[128 * LDT * 2 * sizeof(ushort)];
    __shared__ ushort Ks_hi[BM * LDT], Ks_lo[BM * LDT];   // K hi/lo; reused as S hi/lo
    __shared__ ushort Vt_hi[BM * LDT], Vt_lo[BM * LDT];   // V' transposed [dc][c]
    ushort* Rs_hi = (ushort*)regA;
    ushort* Rs_lo = (ushort*)(regA + 128 * LDT * sizeof(ushort));
    float*  Bst   = (float*)regA;                         // [128][LDB]

    const int tid  = threadIdx.x;
    const int bh   = blockIdx.y;
    const int bix  = blockIdx.x;
    const int i0   = bix * BM;
    const size_t base = (size_t)bh * N * D;

    const int lane = tid & 63;
    const int wv   = tid >> 6;
    const int band = wv * 16;
    const int x    = lane & 15;
    const int quad = lane >> 4;

    // ---- stage normalized Q (into region A), grab A-frags, release region ----
    stage_norm_split(qg + base + (size_t)i0 * D, Rs_hi, Rs_lo, tid);
    __syncthreads();
    const short8 qh0 = *(const short8*)&Rs_hi[(band + x) * LDT + quad * 8];
    const short8 qh1 = *(const short8*)&Rs_hi[(band + x) * LDT + 32 + quad * 8];
    const short8 ql0 = *(const short8*)&Rs_lo[(band + x) * LDT + quad * 8];
    const short8 ql1 = *(const short8*)&Rs_lo[(band + x) * LDT + 32 + quad * 8];
    __syncthreads();

    float4v oacc[4] = {};
    float   pden[4] = {};

    for (int jt = 0; jt <= bix; ++jt) {
        const int j0 = jt * BM;

        // ---- stage K (normalized hi/lo), rpe window hi/lo, V' hi/lo ----
        stage_norm_split(kg + base + (size_t)j0 * D, Ks_hi, Ks_lo, tid);
        {
            const int rel0 = i0 - j0 + (N - 1) - 63;
            for (int u = tid; u < 128 * 4; u += 256) {
                const int row = u >> 2, seg = u & 3;
                int gr = rel0 + row;
                if (gr > 2 * N - 2) gr = 2 * N - 2;   // w=127 value never read
                const float4* p = (const float4*)(rg + (size_t)gr * D + seg * 16);
                float4 f[4] = {p[0], p[1], p[2], p[3]};
                unsigned* ph = (unsigned*)&Rs_hi[row * LDT + seg * 16];
                unsigned* pl = (unsigned*)&Rs_lo[row * LDT + seg * 16];
#pragma unroll
                for (int i = 0; i < 4; ++i) {
                    float va[4] = {f[i].x, f[i].y, f[i].z, f[i].w};
                    ushort hh[4], ll[4];
#pragma unroll
                    for (int j = 0; j < 4; ++j) split2(va[j], hh[j], ll[j]);
                    ph[2 * i]     = (unsigned)hh[0] | ((unsigned)hh[1] << 16);
                    ph[2 * i + 1] = (unsigned)hh[2] | ((unsigned)hh[3] << 16);
                    pl[2 * i]     = (unsigned)ll[0] | ((unsigned)ll[1] << 16);
                    pl[2 * i + 1] = (unsigned)ll[2] | ((unsigned)ll[3] << 16);
                }
            }
        }
        {
            const int c = tid >> 2, seg = tid & 3;
            const float4* pv = (const float4*)(vg + base + (size_t)(j0 + c) * D + seg * 16);
            const float4* pn = (const float4*)(ng + base + (size_t)(j0 + c) * D + seg * 16);
#pragma unroll
            for (int i = 0; i < 4; ++i) {
                float4 fv = pv[i], fn = pn[i];
                float va[4] = {fv.x + 0.1f * fn.x, fv.y + 0.1f * fn.y,
                               fv.z + 0.1f * fn.z, fv.w + 0.1f * fn.w};
                const int dc0 = seg * 16 + i * 4;
#pragma unroll
                for (int j = 0; j < 4; ++j) {
                    ushort hh, ll;
                    split2(va[j], hh, ll);
                    Vt_hi[(dc0 + j) * LDT + c] = hh;
                    Vt_lo[(dc0 + j) * LDT + c] = ll;
                }
            }
        }
        __syncthreads();  // A

        // ---- QK^T ----
        float4v sacc[4];
#pragma unroll
        for (int nt = 0; nt < 4; ++nt) {
            float4v c = {};
            sacc[nt] = mm6(qh0, qh1, ql0, ql1, Ks_hi, Ks_lo,
                           (nt * 16 + x) * LDT + quad * 8, c);
        }
        // ---- QR (B127 frags) ----
        float4v racc[8];
#pragma unroll
        for (int wt = 0; wt < 8; ++wt) {
            float4v c = {};
            racc[wt] = mm6(qh0, qh1, ql0, ql1, Rs_hi, Rs_lo,
                           (wt * 16 + x) * LDT + quad * 8, c);
        }
        __syncthreads();  // B: Rs/Ks MFMA reads done

        // ---- write Bst[w][r] fp32 over region A ----
#pragma unroll
        for (int wt = 0; wt < 8; ++wt)
            *(float4v*)&Bst[(wt * 16 + x) * LDB + band + quad * 4] = racc[wt];
        __syncthreads();  // C

        // ---- gather bias, assemble S (fp32), denom, store S hi/lo over Ks ----
        const bool diag = (jt == bix);
#pragma unroll
        for (int nt = 0; nt < 4; ++nt) {
            const int c = nt * 16 + x;
#pragma unroll
            for (int rr = 0; rr < 4; ++rr) {
                const int r = band + quad * 4 + rr;
                const int w = r - c + 63;
                float s = sacc[nt][rr] + Bst[w * LDB + r] + 1.0f;
                if (diag && c > r) s = 0.f;
                pden[rr] += s;
                ushort sh, sl;
                split2(s, sh, sl);
                Ks_hi[r * LDT + c] = sh;
                Ks_lo[r * LDT + c] = sl;
            }
        }
        __syncthreads();  // D: S visible

        // ---- O += S @ V' ----
        const short8 sh0 = *(const short8*)&Ks_hi[(band + x) * LDT + quad * 8];
        const short8 sh1 = *(const short8*)&Ks_hi[(band + x) * LDT + 32 + quad * 8];
        const short8 sl0 = *(const short8*)&Ks_lo[(band + x) * LDT + quad * 8];
        const short8 sl1 = *(const short8*)&Ks_lo[(band + x) * LDT + 32 + quad * 8];
#pragma unroll
        for (int nt = 0; nt < 4; ++nt)
            oacc[nt] = mm6(sh0, sh1, sl0, sl1, Vt_hi, Vt_lo,
                           (nt * 16 + x) * LDT + quad * 8, oacc[nt]);
        __syncthreads();  // E
    }

    // ---- denominators: reduce over the 16 lanes of this quad ----
    float inv[4];
#pragma unroll
    for (int rr = 0; rr < 4; ++rr) {
        float d = pden[rr];
        d += __shfl_xor(d, 1, 16);
        d += __shfl_xor(d, 2, 16);
        d += __shfl_xor(d, 4, 16);
        d += __shfl_xor(d, 8, 16);
        inv[rr] = 1.0f / d;
    }

    float* outp = og + base + (size_t)i0 * D;
#pragma unroll
    for (int nt = 0; nt < 4; ++nt)
#pragma unroll
        for (int rr = 0; rr < 4; ++rr)
            outp[(size_t)(band + quad * 4 + rr) * D + nt * 16 + x] = oacc[nt][rr] * inv[rr];
}

extern "C" void kernel_launch(void* const* d_in, const int* in_sizes, int n_in,
                              void* d_out, int out_size, void* d_ws, size_t ws_size,
                              hipStream_t stream) {
    const float* q   = (const float*)d_in[0];
    const float* k   = (const float*)d_in[1];
    const float* v   = (const float*)d_in[2];
    const float* dn  = (const float*)d_in[3];
    const float* rpe = (const float*)d_in[4];
    float* out = (float*)d_out;
    const int bh = in_sizes[0] / (N * D);   // 4*16 = 64
    dim3 grid(N / BM, bh);
    fastmax_mfma3<<<grid, dim3(256), 0, stream>>>(q, k, v, dn, rpe, out);
}